// Round 9
// baseline (100.999 us; speedup 1.0000x reference)
//
#include <hip/hip_runtime.h>
#include <math.h>

// CapsShapeLayer: B=256, D=10, M=32, P=36, I=8, O=16, 3 routing iters
// R9: 3-kernel pipeline through d_ws for max TLP.
//   K1 (grid B, 512thr, 2 barriers): ybar -> s1 -> v1 -> z1 -> ws
//   K2 (grid 2B, 576thr, 0 barriers): rinv^T[b][p][m] = 1/sum_d exp(x.z1) -> ws
//   K3 (grid B*D, 64thr, 0 barriers): per-(b,d) tail, all in-wave reductions
// XCD swizzle: batch b pinned to XCD b%8 across all three kernels.
#define BB 256
#define DD 10
#define MM 32
#define PP 36
#define PH2 18
#define II 8
#define OO 16

// ws layout (floats)
#define Z1_OFF   0                      // [B][D][M][I]  655360 floats
#define RINV_OFF (BB*DD*MM*II)          // [B][P][M]     294912 floats

__device__ __forceinline__ float dot8(const float4 a0, const float4 a1,
                                      const float4 b0, const float4 b1) {
    return a0.x*b0.x + a0.y*b0.y + a0.z*b0.z + a0.w*b0.w
         + a1.x*b1.x + a1.y*b1.y + a1.z*b1.z + a1.w*b1.w;
}

// ================= K1: per-batch prework =================
__global__ void __launch_bounds__(512, 1) k1_prework(
    const float* __restrict__ x, const float* __restrict__ W,
    float* __restrict__ ws)
{
    const int b   = blockIdx.x;
    const int tid = threadIdx.x;
    const float* __restrict__ xb = x + (size_t)b * (MM*PP*II);
    __shared__ __align__(16) float ybar[MM*II];
    __shared__ __align__(16) float v_l [DD*OO];

    // ybar[m,i] = 0.1 * sum_p x[m,p,i]   (512 thr = (m, i, p-half), xor(1) combine)
    {
        const int m = tid >> 4, i = (tid >> 1) & 7, ph = tid & 1;
        const float* xr = xb + (m*PP + ph*PH2)*II + i;
        float acc = 0.f;
        #pragma unroll
        for (int q = 0; q < PH2; ++q) acc += xr[q*II];
        acc += __shfl_xor(acc, 1, 64);
        if (ph == 0) ybar[m*II + i] = 0.1f * acc;
    }
    __syncthreads();

    // s1[d,o] -> v1 = squash   (320 thr = (d, o, m-half))
    if (tid < DD*OO*2) {
        const int d = tid >> 5, o = (tid >> 1) & 15, mh = tid & 1;
        float s1 = 0.f;
        #pragma unroll
        for (int j = 0; j < 16; ++j) {
            const int m = mh*16 + j;
            const float4* wp = (const float4*)(W + ((size_t)((d*MM + m)*OO + o)) * II);
            const float4* yp = (const float4*)(ybar + m*II);
            s1 += dot8(wp[0], wp[1], yp[0], yp[1]);
        }
        s1 += __shfl_xor(s1, 1, 64);              // combine m-halves
        float sq = s1 * s1;                        // squash over o (bits 1-4)
        sq += __shfl_xor(sq, 2, 64);
        sq += __shfl_xor(sq, 4, 64);
        sq += __shfl_xor(sq, 8, 64);
        sq += __shfl_xor(sq, 16, 64);
        v_l[d*OO + o] = (sq / (1.f + sq)) * (s1 / sqrtf(sq + 1e-7f));
    }
    __syncthreads();

    // z1[d,m,i] = sum_o W[d,m,o,i]*v1[d,o] -> ws   (640 float4 slots over 512 thr)
    float* __restrict__ z1 = ws + Z1_OFF + (size_t)b * (DD*MM*II);
    for (int s = tid; s < DD*MM*2; s += 512) {
        const int d = s >> 6, r = s & 63, mz = r >> 1, ih = r & 1;
        const float4 vv0 = *(const float4*)(v_l + d*OO);
        const float4 vv1 = *(const float4*)(v_l + d*OO + 4);
        const float4 vv2 = *(const float4*)(v_l + d*OO + 8);
        const float4 vv3 = *(const float4*)(v_l + d*OO + 12);
        const float vs[16] = {vv0.x,vv0.y,vv0.z,vv0.w, vv1.x,vv1.y,vv1.z,vv1.w,
                              vv2.x,vv2.y,vv2.z,vv2.w, vv3.x,vv3.y,vv3.z,vv3.w};
        const float* wz = W + ((size_t)((d*MM + mz)*OO)) * II + ih*4;
        float a0 = 0.f, a1 = 0.f, a2 = 0.f, a3 = 0.f;
        #pragma unroll
        for (int o2 = 0; o2 < OO; ++o2) {
            const float4 wv = *(const float4*)(wz + o2*II);
            a0 += wv.x * vs[o2]; a1 += wv.y * vs[o2];
            a2 += wv.z * vs[o2]; a3 += wv.w * vs[o2];
        }
        *(float4*)(z1 + (d*MM + mz)*II + ih*4) = make_float4(a0, a1, a2, a3);
    }
}

// ================= K2: rinv^T, zero barriers =================
__global__ void __launch_bounds__(576) k2_rinv(
    const float* __restrict__ x, const float* __restrict__ ws_in,
    float* __restrict__ ws)
{
    // physical block -> (b, p-half) with b%8 == phys%8 (XCD pinning)
    const int q   = blockIdx.x;
    const int xcd = q & 7, r = q >> 3;
    const int ph  = r & 1, b = xcd + 8*(r >> 1);
    const int t   = threadIdx.x;                  // 576 = 32 m * 18 p
    const int m   = t / PH2, p = ph*PH2 + (t - (t/PH2)*PH2);

    const float4* xp = (const float4*)(x + ((size_t)b*MM*PP + m*PP + p) * II);
    const float4 x0 = xp[0], x1 = xp[1];
    const float* __restrict__ z1 = ws_in + Z1_OFF + (size_t)b * (DD*MM*II);
    float se = 0.f;
    #pragma unroll
    for (int d = 0; d < DD; ++d) {
        const float4* zp = (const float4*)(z1 + (d*MM + m)*II);
        se += __expf(dot8(x0, x1, zp[0], zp[1]));  // |b1| small -> no max needed
    }
    ws[RINV_OFF + (size_t)b*(PP*MM) + p*MM + m] = 1.0f / se;
}

// ================= K3: per-(b,d) tail, one wave, zero barriers =================
__global__ void __launch_bounds__(64, 4) k3_tail(
    const float* __restrict__ x, const float* __restrict__ W,
    const float* __restrict__ ws, float* __restrict__ out)
{
    // physical block -> (b, d) with b%8 == phys%8 (XCD pinning)
    const int pb  = blockIdx.x;
    const int xcd = pb & 7, idx = pb >> 3;
    const int bq  = idx & 31, d = idx >> 5, b = xcd + 8*bq;
    const int lane = threadIdx.x;

    __shared__ __align__(16) float y  [MM*II];    // 1024 B
    __shared__ __align__(16) float v_l[OO];       //   64 B

    const float* __restrict__ xb = x + (size_t)b * (MM*PP*II);
    const float* __restrict__ z1 = ws + Z1_OFF + (size_t)b*(DD*MM*II) + d*(MM*II);
    const float* __restrict__ ri = ws + RINV_OFF + (size_t)b*(PP*MM);

    const int mF = lane & 31, ph = lane >> 5;     // lane owns (m, p-half)
    const float* xr = xb + (mF*PP + ph*PH2)*II;   // 18 full x-rows
    const float4 zf0 = *(const float4*)(z1 + mF*II);
    const float4 zf1 = *(const float4*)(z1 + mF*II + 4);

    // ---- y2[m,:] = sum_p softmax_d(b1) * x ----
    {
        float a0=0.f,a1=0.f,a2=0.f,a3=0.f,a4=0.f,a5=0.f,a6=0.f,a7=0.f;
        #pragma unroll
        for (int qk = 0; qk < PH2; ++qk) {
            const float4 x0 = *(const float4*)(xr + qk*II);
            const float4 x1 = *(const float4*)(xr + qk*II + 4);
            const float e = __expf(dot8(x0, x1, zf0, zf1)) * ri[(ph*PH2 + qk)*MM + mF];
            a0 += e*x0.x; a1 += e*x0.y; a2 += e*x0.z; a3 += e*x0.w;
            a4 += e*x1.x; a5 += e*x1.y; a6 += e*x1.z; a7 += e*x1.w;
        }
        a0 += __shfl_xor(a0, 32, 64); a1 += __shfl_xor(a1, 32, 64);
        a2 += __shfl_xor(a2, 32, 64); a3 += __shfl_xor(a3, 32, 64);
        a4 += __shfl_xor(a4, 32, 64); a5 += __shfl_xor(a5, 32, 64);
        a6 += __shfl_xor(a6, 32, 64); a7 += __shfl_xor(a7, 32, 64);
        const float4 wv = ph ? make_float4(a4,a5,a6,a7) : make_float4(a0,a1,a2,a3);
        *(float4*)(y + mF*II + ph*4) = wv;
    }
    // single wave: LDS write->read ordered by lgkmcnt, no barrier anywhere

    // ---- s2 -> v2 ----
    const int o = lane & 15, qq = lane >> 4;
    float s2 = 0.f;
    #pragma unroll
    for (int j = 0; j < 8; ++j) {
        const int m = qq*8 + j;
        const float4* wp = (const float4*)(W + ((size_t)((d*MM + m)*OO + o)) * II);
        const float4* yp = (const float4*)(y + m*II);
        s2 += dot8(wp[0], wp[1], yp[0], yp[1]);
    }
    s2 += __shfl_xor(s2, 16, 64);
    s2 += __shfl_xor(s2, 32, 64);
    float sq = s2 * s2;
    sq += __shfl_xor(sq, 1, 64);
    sq += __shfl_xor(sq, 2, 64);
    sq += __shfl_xor(sq, 4, 64);
    sq += __shfl_xor(sq, 8, 64);
    const float v2 = (sq / (1.f + sq)) * (s2 / sqrtf(sq + 1e-7f));
    if (lane < OO) v_l[lane] = v2;
    const float4 vv0 = *(const float4*)(v_l);
    const float4 vv1 = *(const float4*)(v_l + 4);
    const float4 vv2 = *(const float4*)(v_l + 8);
    const float4 vv3 = *(const float4*)(v_l + 12);
    const float vs[16] = {vv0.x,vv0.y,vv0.z,vv0.w, vv1.x,vv1.y,vv1.z,vv1.w,
                          vv2.x,vv2.y,vv2.z,vv2.w, vv3.x,vv3.y,vv3.z,vv3.w};

    // ---- z2 in registers: lane does o-half of its m, xor(32) combine ----
    float4 zf20, zf21;
    {
        const float* wz = W + ((size_t)(d*MM + mF)*OO) * II;
        float b0=0.f,b1=0.f,b2=0.f,b3=0.f,b4=0.f,b5=0.f,b6=0.f,b7=0.f;
        #pragma unroll
        for (int j = 0; j < 8; ++j) {
            const int o2 = ph*8 + j;
            const float4 w0 = *(const float4*)(wz + o2*II);
            const float4 w1 = *(const float4*)(wz + o2*II + 4);
            const float sv = vs[o2];
            b0 += w0.x*sv; b1 += w0.y*sv; b2 += w0.z*sv; b3 += w0.w*sv;
            b4 += w1.x*sv; b5 += w1.y*sv; b6 += w1.z*sv; b7 += w1.w*sv;
        }
        b0 += __shfl_xor(b0, 32, 64); b1 += __shfl_xor(b1, 32, 64);
        b2 += __shfl_xor(b2, 32, 64); b3 += __shfl_xor(b3, 32, 64);
        b4 += __shfl_xor(b4, 32, 64); b5 += __shfl_xor(b5, 32, 64);
        b6 += __shfl_xor(b6, 32, 64); b7 += __shfl_xor(b7, 32, 64);
        zf20 = make_float4(zf0.x + b0, zf0.y + b1, zf0.z + b2, zf0.w + b3);
        zf21 = make_float4(zf1.x + b4, zf1.y + b5, zf1.z + b6, zf1.w + b7);
    }

    // ---- final softmax over P ----
    {
        float se = 0.f;
        float a0=0.f,a1=0.f,a2=0.f,a3=0.f,a4=0.f,a5=0.f,a6=0.f,a7=0.f;
        #pragma unroll
        for (int qk = 0; qk < PH2; ++qk) {
            const float4 x0 = *(const float4*)(xr + qk*II);
            const float4 x1 = *(const float4*)(xr + qk*II + 4);
            const float e = __expf(dot8(x0, x1, zf20, zf21));
            se += e;
            a0 += e*x0.x; a1 += e*x0.y; a2 += e*x0.z; a3 += e*x0.w;
            a4 += e*x1.x; a5 += e*x1.y; a6 += e*x1.z; a7 += e*x1.w;
        }
        se += __shfl_xor(se, 32, 64);
        a0 += __shfl_xor(a0, 32, 64); a1 += __shfl_xor(a1, 32, 64);
        a2 += __shfl_xor(a2, 32, 64); a3 += __shfl_xor(a3, 32, 64);
        a4 += __shfl_xor(a4, 32, 64); a5 += __shfl_xor(a5, 32, 64);
        a6 += __shfl_xor(a6, 32, 64); a7 += __shfl_xor(a7, 32, 64);
        const float rs = 1.f / se;
        const float4 wv = ph ? make_float4(a4*rs,a5*rs,a6*rs,a7*rs)
                             : make_float4(a0*rs,a1*rs,a2*rs,a3*rs);
        *(float4*)(y + mF*II + ph*4) = wv;
    }

    // ---- s3 -> squash -> out ----
    float s3 = 0.f;
    #pragma unroll
    for (int j = 0; j < 8; ++j) {
        const int m = qq*8 + j;
        const float4* wp = (const float4*)(W + ((size_t)((d*MM + m)*OO + o)) * II);
        const float4* yp = (const float4*)(y + m*II);
        s3 += dot8(wp[0], wp[1], yp[0], yp[1]);
    }
    s3 += __shfl_xor(s3, 16, 64);
    s3 += __shfl_xor(s3, 32, 64);
    float sq3 = s3 * s3;
    sq3 += __shfl_xor(sq3, 1, 64);
    sq3 += __shfl_xor(sq3, 2, 64);
    sq3 += __shfl_xor(sq3, 4, 64);
    sq3 += __shfl_xor(sq3, 8, 64);
    const float r = (sq3 / (1.f + sq3)) * (s3 / sqrtf(sq3 + 1e-7f));
    if (lane < OO)
        out[((size_t)b*DD + d)*OO + o] = r;
}

extern "C" void kernel_launch(void* const* d_in, const int* in_sizes, int n_in,
                              void* d_out, int out_size, void* d_ws, size_t ws_size,
                              hipStream_t stream) {
    (void)in_sizes; (void)n_in; (void)out_size; (void)ws_size;
    const float* x = (const float*)d_in[0];  // (B, M, P, I)
    const float* W = (const float*)d_in[1];  // (1, D, M, 1, O, I)
    float* out = (float*)d_out;              // (B, D, O)
    float* wsf = (float*)d_ws;               // >= 3.8 MB used
    k1_prework<<<dim3(BB),     dim3(512), 0, stream>>>(x, W, wsf);
    k2_rinv   <<<dim3(BB*2),   dim3(576), 0, stream>>>(x, wsf, wsf);
    k3_tail   <<<dim3(BB*DD),  dim3(64),  0, stream>>>(x, W, wsf, out);
}

// Round 10
// 79.244 us; speedup vs baseline: 1.2745x; 1.2745x over previous
//
#include <hip/hip_runtime.h>
#include <math.h>

// CapsShapeLayer: B=256, D=10, M=32, P=36, I=8, O=16, 3 routing iters
// R10: R8 skeleton (1 block/batch, 10 waves, wave owns d) + XOR-swizzled x
// layout (conflict-free tail reads at the 8-cycle LDS floor) + ybar computed
// from LDS instead of 144 strided global loads. 4 barriers.
#define BB 256
#define DD 10
#define MM 32
#define PP 36
#define PH2 18
#define II 8
#define OO 16
#define NT 640        // 10 waves = one per d
#define XS 288        // xs row stride in floats (no pad; swizzle does the spreading)
#define RS 37         // rinv row stride: gcd(5,32)=1 -> conflict-free over m
// chunk c (16B unit, 0..71) of row m lives at float offset SWZ(m,c)
#define SWZ(m, c) ((((c) ^ ((m) & 7))) << 2)

__device__ __forceinline__ float dot8(const float4 a0, const float4 a1,
                                      const float4 b0, const float4 b1) {
    return a0.x*b0.x + a0.y*b0.y + a0.z*b0.z + a0.w*b0.w
         + a1.x*b1.x + a1.y*b1.y + a1.z*b1.z + a1.w*b1.w;
}

__global__ void __launch_bounds__(NT, 3) caps_routing(
    const float* __restrict__ x,   // (B, M, P, I)
    const float* __restrict__ W,   // (D, M, O, I)
    float* __restrict__ out)       // (B, D, O)
{
    const int bidx = blockIdx.x;
    const int tid  = threadIdx.x;
    const int wave = tid >> 6;          // d owned by this wave (0..9)
    const int lane = tid & 63;
    const float* __restrict__ xb = x + (size_t)bidx * (MM*PP*II);

    __shared__ __align__(16) float xs  [MM*XS];     // 36864 B  x staged once (swizzled)
    __shared__ __align__(16) float z   [DD*MM*II];  // 10240 B  z1 (rinv needs all d)
    __shared__ __align__(16) float y   [DD*MM*II];  // 10240 B  per-wave y scratch
    __shared__ __align__(16) float ybar[MM*II];     //  1024 B
    __shared__ __align__(16) float rinv[MM*RS];     //  4736 B
    __shared__ __align__(16) float v_l [DD*OO];     //   640 B
    // total 63744 B

    // ======== stage 0: x -> LDS, swizzled ========
    {
        const float4* xg = (const float4*)xb;
        #pragma unroll
        for (int k = 0; k < 4; ++k) {                 // 2304 float4 over 640 thr
            const int t = tid + k*NT;
            if (t < MM*72) {
                const int m = t / 72, c = t - m*72;
                *(float4*)(xs + m*XS + SWZ(m, c)) = xg[t];
            }
        }
    }
    __syncthreads();                                  // BARRIER 1

    // ======== ybar[m,i] = 0.1 * sum_p x[m,p,i]  (from LDS, <=2-way banks) ========
    if (tid < MM*II) {
        const int m = tid >> 3, i = tid & 7;
        const int hi = i >> 2, lo = i & 3;
        const float* xrow = xs + m*XS;
        float acc = 0.f;
        #pragma unroll 6
        for (int p = 0; p < PP; ++p) acc += xrow[SWZ(m, 2*p + hi) + lo];
        ybar[tid] = 0.1f * acc;
    }
    __syncthreads();                                  // BARRIER 2

    // ======== per-wave (d = wave): s1 -> v1 -> z1 ========
    {
        const int d = wave;
        const int o = lane & 15, qq = lane >> 4;      // o bits 0-3, m-quarter bits 4-5
        float s1 = 0.f;
        #pragma unroll
        for (int j = 0; j < 8; ++j) {
            const int m = qq*8 + j;
            const float4* wp = (const float4*)(W + ((size_t)((d*MM + m)*OO + o)) * II);
            const float4* yp = (const float4*)(ybar + m*II);
            s1 += dot8(wp[0], wp[1], yp[0], yp[1]);
        }
        s1 += __shfl_xor(s1, 16, 64);
        s1 += __shfl_xor(s1, 32, 64);
        float sq = s1 * s1;
        sq += __shfl_xor(sq, 1, 64);
        sq += __shfl_xor(sq, 2, 64);
        sq += __shfl_xor(sq, 4, 64);
        sq += __shfl_xor(sq, 8, 64);
        const float v1 = (sq / (1.f + sq)) * (s1 / sqrtf(sq + 1e-7f));
        if (lane < OO) v_l[d*OO + lane] = v1;         // stage v for broadcast reads

        // z1: lane = (m, i-half); W as b128 over o; v via 4 broadcast b128 reads
        const float4 vv0 = *(const float4*)(v_l + d*OO);
        const float4 vv1 = *(const float4*)(v_l + d*OO + 4);
        const float4 vv2 = *(const float4*)(v_l + d*OO + 8);
        const float4 vv3 = *(const float4*)(v_l + d*OO + 12);
        const float vs[16] = {vv0.x,vv0.y,vv0.z,vv0.w, vv1.x,vv1.y,vv1.z,vv1.w,
                              vv2.x,vv2.y,vv2.z,vv2.w, vv3.x,vv3.y,vv3.z,vv3.w};
        const int mz = lane >> 1, ihz = lane & 1;
        const float* wz = W + ((size_t)(d*MM + mz)*OO) * II + ihz*4;
        float a0 = 0.f, a1 = 0.f, a2 = 0.f, a3 = 0.f;
        #pragma unroll
        for (int o2 = 0; o2 < OO; ++o2) {
            const float4 wv = *(const float4*)(wz + o2*II);
            a0 += wv.x * vs[o2]; a1 += wv.y * vs[o2];
            a2 += wv.z * vs[o2]; a3 += wv.w * vs[o2];
        }
        *(float4*)(z + (d*MM + mz)*II + ihz*4) = make_float4(a0, a1, a2, a3);
    }
    __syncthreads();                                  // BARRIER 3

    // ======== rinv[m,p] = 1 / sum_d exp(x.z1)  (z reads ~broadcast over lanes) ========
    #pragma unroll
    for (int k = 0; k < 2; ++k) {
        const int t = tid + k*NT;
        if (t < MM*PP) {
            const int m = t / PP, p = t - m*PP;
            const float4 x0 = *(const float4*)(xs + m*XS + SWZ(m, 2*p));
            const float4 x1 = *(const float4*)(xs + m*XS + SWZ(m, 2*p + 1));
            float se = 0.f;
            #pragma unroll
            for (int d2 = 0; d2 < DD; ++d2) {
                const float4* zp = (const float4*)(z + (d2*MM + m)*II);
                se += __expf(dot8(x0, x1, zp[0], zp[1]));  // |b1| small -> no max
            }
            rinv[m*RS + p] = 1.0f / se;
        }
    }
    __syncthreads();                                  // BARRIER 4 (last)

    // ======== tail (d = wave): y2 -> s2 -> v2 -> z2(regs) -> final -> s3 -> out ========
    {
        const int d = wave;
        const float* __restrict__ zd = z + d*(MM*II);
        float* __restrict__ yd = y + d*(MM*II);

        const int mF = lane & 31;                     // m owned by this lane
        const int ph = lane >> 5;                     // p-half (0/1), partner = lane^32
        const float* xrow = xs + mF*XS;
        const float4 zf0 = *(const float4*)(zd + mF*II);
        const float4 zf1 = *(const float4*)(zd + mF*II + 4);

        // ---- y2: full dot8 per lane, 18 iters, conflict-free swizzled reads ----
        {
            const float* rr = rinv + mF*RS + ph*PH2;
            float a0=0.f,a1=0.f,a2=0.f,a3=0.f,a4=0.f,a5=0.f,a6=0.f,a7=0.f;
            #pragma unroll 6
            for (int q = 0; q < PH2; ++q) {
                const int p = ph*PH2 + q;
                const float4 x0 = *(const float4*)(xrow + SWZ(mF, 2*p));
                const float4 x1 = *(const float4*)(xrow + SWZ(mF, 2*p + 1));
                const float e = __expf(dot8(x0, x1, zf0, zf1)) * rr[q];
                a0 += e*x0.x; a1 += e*x0.y; a2 += e*x0.z; a3 += e*x0.w;
                a4 += e*x1.x; a5 += e*x1.y; a6 += e*x1.z; a7 += e*x1.w;
            }
            a0 += __shfl_xor(a0, 32, 64); a1 += __shfl_xor(a1, 32, 64);
            a2 += __shfl_xor(a2, 32, 64); a3 += __shfl_xor(a3, 32, 64);
            a4 += __shfl_xor(a4, 32, 64); a5 += __shfl_xor(a5, 32, 64);
            a6 += __shfl_xor(a6, 32, 64); a7 += __shfl_xor(a7, 32, 64);
            const float4 wv = ph ? make_float4(a4,a5,a6,a7) : make_float4(a0,a1,a2,a3);
            *(float4*)(yd + mF*II + ph*4) = wv;       // two lanes write the two halves
        }
        // in-wave LDS write->read ordering via lgkmcnt; no barrier

        // ---- s2 -> v2 ----
        const int o = lane & 15, qq = lane >> 4;
        float s2 = 0.f;
        #pragma unroll
        for (int j = 0; j < 8; ++j) {
            const int m = qq*8 + j;
            const float4* wp = (const float4*)(W + ((size_t)((d*MM + m)*OO + o)) * II);
            const float4* yp = (const float4*)(yd + m*II);
            s2 += dot8(wp[0], wp[1], yp[0], yp[1]);
        }
        s2 += __shfl_xor(s2, 16, 64);
        s2 += __shfl_xor(s2, 32, 64);
        float sq = s2 * s2;
        sq += __shfl_xor(sq, 1, 64);
        sq += __shfl_xor(sq, 2, 64);
        sq += __shfl_xor(sq, 4, 64);
        sq += __shfl_xor(sq, 8, 64);
        const float v2 = (sq / (1.f + sq)) * (s2 / sqrtf(sq + 1e-7f));
        if (lane < OO) v_l[d*OO + lane] = v2;
        const float4 vv0 = *(const float4*)(v_l + d*OO);
        const float4 vv1 = *(const float4*)(v_l + d*OO + 4);
        const float4 vv2 = *(const float4*)(v_l + d*OO + 8);
        const float4 vv3 = *(const float4*)(v_l + d*OO + 12);
        const float vs[16] = {vv0.x,vv0.y,vv0.z,vv0.w, vv1.x,vv1.y,vv1.z,vv1.w,
                              vv2.x,vv2.y,vv2.z,vv2.w, vv3.x,vv3.y,vv3.z,vv3.w};

        // ---- z2: lane (mF, ph) does its o-half, xor(32) combine -> full z in regs ----
        float4 zf20, zf21;
        {
            const float* wz = W + ((size_t)(d*MM + mF)*OO) * II;
            float b0=0.f,b1=0.f,b2=0.f,b3=0.f,b4=0.f,b5=0.f,b6=0.f,b7=0.f;
            #pragma unroll
            for (int j = 0; j < 8; ++j) {
                const int o2 = ph*8 + j;
                const float4 w0 = *(const float4*)(wz + o2*II);
                const float4 w1 = *(const float4*)(wz + o2*II + 4);
                const float sv = vs[o2];
                b0 += w0.x*sv; b1 += w0.y*sv; b2 += w0.z*sv; b3 += w0.w*sv;
                b4 += w1.x*sv; b5 += w1.y*sv; b6 += w1.z*sv; b7 += w1.w*sv;
            }
            b0 += __shfl_xor(b0, 32, 64); b1 += __shfl_xor(b1, 32, 64);
            b2 += __shfl_xor(b2, 32, 64); b3 += __shfl_xor(b3, 32, 64);
            b4 += __shfl_xor(b4, 32, 64); b5 += __shfl_xor(b5, 32, 64);
            b6 += __shfl_xor(b6, 32, 64); b7 += __shfl_xor(b7, 32, 64);
            zf20 = make_float4(zf0.x + b0, zf0.y + b1, zf0.z + b2, zf0.w + b3);
            zf21 = make_float4(zf1.x + b4, zf1.y + b5, zf1.z + b6, zf1.w + b7);
        }

        // ---- final softmax over P: single pass, conflict-free swizzled reads ----
        {
            float se = 0.f;
            float a0=0.f,a1=0.f,a2=0.f,a3=0.f,a4=0.f,a5=0.f,a6=0.f,a7=0.f;
            #pragma unroll 6
            for (int q = 0; q < PH2; ++q) {
                const int p = ph*PH2 + q;
                const float4 x0 = *(const float4*)(xrow + SWZ(mF, 2*p));
                const float4 x1 = *(const float4*)(xrow + SWZ(mF, 2*p + 1));
                const float e = __expf(dot8(x0, x1, zf20, zf21));
                se += e;
                a0 += e*x0.x; a1 += e*x0.y; a2 += e*x0.z; a3 += e*x0.w;
                a4 += e*x1.x; a5 += e*x1.y; a6 += e*x1.z; a7 += e*x1.w;
            }
            se += __shfl_xor(se, 32, 64);
            a0 += __shfl_xor(a0, 32, 64); a1 += __shfl_xor(a1, 32, 64);
            a2 += __shfl_xor(a2, 32, 64); a3 += __shfl_xor(a3, 32, 64);
            a4 += __shfl_xor(a4, 32, 64); a5 += __shfl_xor(a5, 32, 64);
            a6 += __shfl_xor(a6, 32, 64); a7 += __shfl_xor(a7, 32, 64);
            const float rs = 1.f / se;
            const float4 wv = ph ? make_float4(a4*rs,a5*rs,a6*rs,a7*rs)
                                 : make_float4(a0*rs,a1*rs,a2*rs,a3*rs);
            *(float4*)(yd + mF*II + ph*4) = wv;
        }

        // ---- s3 -> squash -> out ----
        float s3 = 0.f;
        #pragma unroll
        for (int j = 0; j < 8; ++j) {
            const int m = qq*8 + j;
            const float4* wp = (const float4*)(W + ((size_t)((d*MM + m)*OO + o)) * II);
            const float4* yp = (const float4*)(yd + m*II);
            s3 += dot8(wp[0], wp[1], yp[0], yp[1]);
        }
        s3 += __shfl_xor(s3, 16, 64);
        s3 += __shfl_xor(s3, 32, 64);
        float sq3 = s3 * s3;
        sq3 += __shfl_xor(sq3, 1, 64);
        sq3 += __shfl_xor(sq3, 2, 64);
        sq3 += __shfl_xor(sq3, 4, 64);
        sq3 += __shfl_xor(sq3, 8, 64);
        const float r = (sq3 / (1.f + sq3)) * (s3 / sqrtf(sq3 + 1e-7f));
        if (lane < OO)
            out[(size_t)bidx * (DD*OO) + d*OO + o] = r;
    }
}

extern "C" void kernel_launch(void* const* d_in, const int* in_sizes, int n_in,
                              void* d_out, int out_size, void* d_ws, size_t ws_size,
                              hipStream_t stream) {
    (void)in_sizes; (void)n_in; (void)out_size; (void)d_ws; (void)ws_size;
    const float* x = (const float*)d_in[0];  // (B, M, P, I)
    const float* W = (const float*)d_in[1];  // (1, D, M, 1, O, I)
    float* out = (float*)d_out;              // (B, D, O)
    caps_routing<<<dim3(BB), dim3(NT), 0, stream>>>(x, W, out);
}

// Round 12
// 77.403 us; speedup vs baseline: 1.3049x; 1.0238x over previous
//
#include <hip/hip_runtime.h>
#include <math.h>

// CapsShapeLayer: B=256, D=10, M=32, P=36, I=8, O=16, 3 routing iters
// R12 = R11 with the __exp2f glibc-macro collision fixed via
// __builtin_amdgcn_exp2f (lowers to v_exp_f32, which is 2^x on AMD).
// Skeleton: 1 block/batch, 10 waves, wave owns d, 3 barriers. Wave caches its
// W[d] s-slice in 64 VGPRs (W passes 5->3, no L2 latency mid-chain); log2(e)
// folded into stored z; XOR-swizzled x LDS (conflict-free tail reads).
#define BB 256
#define DD 10
#define MM 32
#define PP 36
#define PH2 18
#define II 8
#define OO 16
#define NT 640        // 10 waves = one per d
#define XS 288        // xs row stride (swizzle spreads banks; no pad needed)
#define RS 37         // rinv row stride: gcd(5,32)=1 -> conflict-free over m
#define SWZ(m, c) ((((c) ^ ((m) & 7))) << 2)   // chunk c (16B) of row m
#define LOG2E 1.44269504088896f
#define EXP2(v) __builtin_amdgcn_exp2f(v)

__device__ __forceinline__ float dot8(const float4 a0, const float4 a1,
                                      const float4 b0, const float4 b1) {
    return a0.x*b0.x + a0.y*b0.y + a0.z*b0.z + a0.w*b0.w
         + a1.x*b1.x + a1.y*b1.y + a1.z*b1.z + a1.w*b1.w;
}

__global__ void __launch_bounds__(NT, 3) caps_routing(
    const float* __restrict__ x,   // (B, M, P, I)
    const float* __restrict__ W,   // (D, M, O, I)
    float* __restrict__ out)       // (B, D, O)
{
    const int bidx = blockIdx.x;
    const int tid  = threadIdx.x;
    const int wave = tid >> 6;          // d owned by this wave (0..9)
    const int lane = tid & 63;
    const float* __restrict__ xb = x + (size_t)bidx * (MM*PP*II);

    __shared__ __align__(16) float xs  [MM*XS];     // 36864 B  x staged once (swizzled)
    __shared__ __align__(16) float z   [DD*MM*II];  // 10240 B  K*z1 (rinv needs all d)
    __shared__ __align__(16) float y   [DD*MM*II];  // 10240 B  per-wave y scratch
    __shared__ __align__(16) float ybar[MM*II];     //  1024 B
    __shared__ __align__(16) float rinv[MM*RS];     //  4736 B
    __shared__ __align__(16) float v_l [DD*OO];     //   640 B
    // total 63744 B

    const int d  = wave;
    const int o  = lane & 15, qq = lane >> 4;       // s-stage laning: (o, m-quarter)

    // ---- cache this wave's W[d] s-slice in regs: 8 rows (m=qq*8+j) x 32B ----
    float4 wr0[8], wr1[8];
    #pragma unroll
    for (int j = 0; j < 8; ++j) {
        const float4* wp = (const float4*)(W + ((size_t)((d*MM + qq*8 + j)*OO + o)) * II);
        wr0[j] = wp[0]; wr1[j] = wp[1];
    }

    // ======== stage 0: x -> LDS (swizzled) + ybar from global ========
    {
        const float4* xg = (const float4*)xb;
        #pragma unroll
        for (int k = 0; k < 4; ++k) {                 // 2304 float4 over 640 thr
            const int t = tid + k*NT;
            if (t < MM*72) {
                const int m = t / 72, c = t - m*72;
                *(float4*)(xs + m*XS + SWZ(m, c)) = xg[t];
            }
        }
        if (tid < MM*II) {                            // ybar[m,i] = 0.1 * sum_p x
            const int m = tid >> 3, i = tid & 7;
            const float* xr = xb + m*(PP*II) + i;
            float acc = 0.f;
            #pragma unroll 6
            for (int p = 0; p < PP; ++p) acc += xr[p*II];
            ybar[tid] = 0.1f * acc;
        }
    }
    __syncthreads();                                  // BARRIER 1

    // ======== per-wave: s1 (regs) -> v1 -> K*z1 -> LDS ========
    {
        float s1 = 0.f;
        #pragma unroll
        for (int j = 0; j < 8; ++j) {
            const float4* yp = (const float4*)(ybar + (qq*8 + j)*II);
            s1 += dot8(wr0[j], wr1[j], yp[0], yp[1]);
        }
        s1 += __shfl_xor(s1, 16, 64);
        s1 += __shfl_xor(s1, 32, 64);
        float sq = s1 * s1;
        sq += __shfl_xor(sq, 1, 64);
        sq += __shfl_xor(sq, 2, 64);
        sq += __shfl_xor(sq, 4, 64);
        sq += __shfl_xor(sq, 8, 64);
        const float v1 = (sq / (1.f + sq)) * (s1 / sqrtf(sq + 1e-7f));
        if (lane < OO) v_l[d*OO + lane] = v1;

        // z1: lane = (m, i-half); W b128 over o; store K*z1 for exp2
        const float4 vv0 = *(const float4*)(v_l + d*OO);
        const float4 vv1 = *(const float4*)(v_l + d*OO + 4);
        const float4 vv2 = *(const float4*)(v_l + d*OO + 8);
        const float4 vv3 = *(const float4*)(v_l + d*OO + 12);
        const float vs[16] = {vv0.x,vv0.y,vv0.z,vv0.w, vv1.x,vv1.y,vv1.z,vv1.w,
                              vv2.x,vv2.y,vv2.z,vv2.w, vv3.x,vv3.y,vv3.z,vv3.w};
        const int mz = lane >> 1, ihz = lane & 1;
        const float* wz = W + ((size_t)(d*MM + mz)*OO) * II + ihz*4;
        float a0 = 0.f, a1 = 0.f, a2 = 0.f, a3 = 0.f;
        #pragma unroll
        for (int o2 = 0; o2 < OO; ++o2) {
            const float4 wv = *(const float4*)(wz + o2*II);
            a0 += wv.x * vs[o2]; a1 += wv.y * vs[o2];
            a2 += wv.z * vs[o2]; a3 += wv.w * vs[o2];
        }
        *(float4*)(z + (d*MM + mz)*II + ihz*4) =
            make_float4(a0*LOG2E, a1*LOG2E, a2*LOG2E, a3*LOG2E);
    }
    __syncthreads();                                  // BARRIER 2

    // ======== rinv[m,p] = 1 / sum_d exp2(x.(K*z1))  (|b| small -> no max) ========
    #pragma unroll
    for (int k = 0; k < 2; ++k) {
        const int t = tid + k*NT;
        if (t < MM*PP) {
            const int m = t / PP, p = t - m*PP;
            const float4 x0 = *(const float4*)(xs + m*XS + SWZ(m, 2*p));
            const float4 x1 = *(const float4*)(xs + m*XS + SWZ(m, 2*p + 1));
            float se = 0.f;
            #pragma unroll
            for (int d2 = 0; d2 < DD; ++d2) {
                const float4* zp = (const float4*)(z + (d2*MM + m)*II);
                se += EXP2(dot8(x0, x1, zp[0], zp[1]));
            }
            rinv[m*RS + p] = 1.0f / se;
        }
    }
    __syncthreads();                                  // BARRIER 3 (last)

    // ======== tail: y2 -> s2(regs) -> v2 -> z2(regs) -> final -> s3(regs) -> out ========
    {
        const float* __restrict__ zd = z + d*(MM*II);
        float* __restrict__ yd = y + d*(MM*II);

        const int mF = lane & 31;                     // m owned by this lane
        const int ph = lane >> 5;                     // p-half (0/1), partner = lane^32
        const float* xrow = xs + mF*XS;
        const float4 zf0 = *(const float4*)(zd + mF*II);       // K*z1 halves
        const float4 zf1 = *(const float4*)(zd + mF*II + 4);

        // ---- y2: 18 iters, conflict-free swizzled reads, exp2 ----
        {
            const float* rr = rinv + mF*RS + ph*PH2;
            float a0=0.f,a1=0.f,a2=0.f,a3=0.f,a4=0.f,a5=0.f,a6=0.f,a7=0.f;
            #pragma unroll 6
            for (int q = 0; q < PH2; ++q) {
                const int p = ph*PH2 + q;
                const float4 x0 = *(const float4*)(xrow + SWZ(mF, 2*p));
                const float4 x1 = *(const float4*)(xrow + SWZ(mF, 2*p + 1));
                const float e = EXP2(dot8(x0, x1, zf0, zf1)) * rr[q];
                a0 += e*x0.x; a1 += e*x0.y; a2 += e*x0.z; a3 += e*x0.w;
                a4 += e*x1.x; a5 += e*x1.y; a6 += e*x1.z; a7 += e*x1.w;
            }
            a0 += __shfl_xor(a0, 32, 64); a1 += __shfl_xor(a1, 32, 64);
            a2 += __shfl_xor(a2, 32, 64); a3 += __shfl_xor(a3, 32, 64);
            a4 += __shfl_xor(a4, 32, 64); a5 += __shfl_xor(a5, 32, 64);
            a6 += __shfl_xor(a6, 32, 64); a7 += __shfl_xor(a7, 32, 64);
            const float4 wv = ph ? make_float4(a4,a5,a6,a7) : make_float4(a0,a1,a2,a3);
            *(float4*)(yd + mF*II + ph*4) = wv;
        }
        // in-wave LDS write->read ordering via lgkmcnt; no barrier

        // ---- s2 (from regs) -> v2 ----
        float s2 = 0.f;
        #pragma unroll
        for (int j = 0; j < 8; ++j) {
            const float4* yp = (const float4*)(yd + (qq*8 + j)*II);
            s2 += dot8(wr0[j], wr1[j], yp[0], yp[1]);
        }
        s2 += __shfl_xor(s2, 16, 64);
        s2 += __shfl_xor(s2, 32, 64);
        float sq = s2 * s2;
        sq += __shfl_xor(sq, 1, 64);
        sq += __shfl_xor(sq, 2, 64);
        sq += __shfl_xor(sq, 4, 64);
        sq += __shfl_xor(sq, 8, 64);
        const float v2 = (sq / (1.f + sq)) * (s2 / sqrtf(sq + 1e-7f));
        if (lane < OO) v_l[d*OO + lane] = v2;
        const float4 vv0 = *(const float4*)(v_l + d*OO);
        const float4 vv1 = *(const float4*)(v_l + d*OO + 4);
        const float4 vv2 = *(const float4*)(v_l + d*OO + 8);
        const float4 vv3 = *(const float4*)(v_l + d*OO + 12);
        const float vs[16] = {vv0.x,vv0.y,vv0.z,vv0.w, vv1.x,vv1.y,vv1.z,vv1.w,
                              vv2.x,vv2.y,vv2.z,vv2.w, vv3.x,vv3.y,vv3.z,vv3.w};

        // ---- z2: lane (mF, ph) does its o-half (global W), xor(32) combine ----
        float4 zf20, zf21;
        {
            const float* wz = W + ((size_t)(d*MM + mF)*OO) * II;
            float b0=0.f,b1=0.f,b2=0.f,b3=0.f,b4=0.f,b5=0.f,b6=0.f,b7=0.f;
            #pragma unroll
            for (int j = 0; j < 8; ++j) {
                const int o2 = ph*8 + j;
                const float4 w0 = *(const float4*)(wz + o2*II);
                const float4 w1 = *(const float4*)(wz + o2*II + 4);
                const float sv = vs[o2];
                b0 += w0.x*sv; b1 += w0.y*sv; b2 += w0.z*sv; b3 += w0.w*sv;
                b4 += w1.x*sv; b5 += w1.y*sv; b6 += w1.z*sv; b7 += w1.w*sv;
            }
            b0 += __shfl_xor(b0, 32, 64); b1 += __shfl_xor(b1, 32, 64);
            b2 += __shfl_xor(b2, 32, 64); b3 += __shfl_xor(b3, 32, 64);
            b4 += __shfl_xor(b4, 32, 64); b5 += __shfl_xor(b5, 32, 64);
            b6 += __shfl_xor(b6, 32, 64); b7 += __shfl_xor(b7, 32, 64);
            zf20 = make_float4(zf0.x + b0*LOG2E, zf0.y + b1*LOG2E,
                               zf0.z + b2*LOG2E, zf0.w + b3*LOG2E);
            zf21 = make_float4(zf1.x + b4*LOG2E, zf1.y + b5*LOG2E,
                               zf1.z + b6*LOG2E, zf1.w + b7*LOG2E);
        }

        // ---- final softmax over P: single pass, exp2 ----
        {
            float se = 0.f;
            float a0=0.f,a1=0.f,a2=0.f,a3=0.f,a4=0.f,a5=0.f,a6=0.f,a7=0.f;
            #pragma unroll 6
            for (int q = 0; q < PH2; ++q) {
                const int p = ph*PH2 + q;
                const float4 x0 = *(const float4*)(xrow + SWZ(mF, 2*p));
                const float4 x1 = *(const float4*)(xrow + SWZ(mF, 2*p + 1));
                const float e = EXP2(dot8(x0, x1, zf20, zf21));
                se += e;
                a0 += e*x0.x; a1 += e*x0.y; a2 += e*x0.z; a3 += e*x0.w;
                a4 += e*x1.x; a5 += e*x1.y; a6 += e*x1.z; a7 += e*x1.w;
            }
            se += __shfl_xor(se, 32, 64);
            a0 += __shfl_xor(a0, 32, 64); a1 += __shfl_xor(a1, 32, 64);
            a2 += __shfl_xor(a2, 32, 64); a3 += __shfl_xor(a3, 32, 64);
            a4 += __shfl_xor(a4, 32, 64); a5 += __shfl_xor(a5, 32, 64);
            a6 += __shfl_xor(a6, 32, 64); a7 += __shfl_xor(a7, 32, 64);
            const float rs = 1.f / se;
            const float4 wv = ph ? make_float4(a4*rs,a5*rs,a6*rs,a7*rs)
                                 : make_float4(a0*rs,a1*rs,a2*rs,a3*rs);
            *(float4*)(yd + mF*II + ph*4) = wv;
        }

        // ---- s3 (from regs) -> squash -> out ----
        float s3 = 0.f;
        #pragma unroll
        for (int j = 0; j < 8; ++j) {
            const float4* yp = (const float4*)(yd + (qq*8 + j)*II);
            s3 += dot8(wr0[j], wr1[j], yp[0], yp[1]);
        }
        s3 += __shfl_xor(s3, 16, 64);
        s3 += __shfl_xor(s3, 32, 64);
        float sq3 = s3 * s3;
        sq3 += __shfl_xor(sq3, 1, 64);
        sq3 += __shfl_xor(sq3, 2, 64);
        sq3 += __shfl_xor(sq3, 4, 64);
        sq3 += __shfl_xor(sq3, 8, 64);
        const float r = (sq3 / (1.f + sq3)) * (s3 / sqrtf(sq3 + 1e-7f));
        if (lane < OO)
            out[(size_t)bidx * (DD*OO) + d*OO + o] = r;
    }
}

extern "C" void kernel_launch(void* const* d_in, const int* in_sizes, int n_in,
                              void* d_out, int out_size, void* d_ws, size_t ws_size,
                              hipStream_t stream) {
    (void)in_sizes; (void)n_in; (void)out_size; (void)d_ws; (void)ws_size;
    const float* x = (const float*)d_in[0];  // (B, M, P, I)
    const float* W = (const float*)d_in[1];  // (1, D, M, 1, O, I)
    float* out = (float*)d_out;              // (B, D, O)
    caps_routing<<<dim3(BB), dim3(NT), 0, stream>>>(x, W, out);
}